// Round 6
// baseline (508.161 us; speedup 1.0000x reference)
//
#include <hip/hip_runtime.h>
#include <math.h>

// Problem constants (fixed by setup_inputs)
#define B_  32
#define N_  20000
#define C_  8
#define E_  512
#define H_  8
#define SCALE 0.125f   // 1/sqrt(64)

#define CHUNK 512
#define NCH   40       // ceil(20000/512)  (top-k chunking)
#define NC3   157      // ceil(20000/128)  (GEMM n-chunks, BN=128)
#define SSZ ((size_t)B_ * H_ * N_)   // per-class S floats (256*20000)

typedef __attribute__((ext_vector_type(8)))  short bf8_t;    // 8 bf16 (4 VGPRs)
typedef __attribute__((ext_vector_type(16))) float f32x16;   // 32x32 MFMA acc

// async global->LDS, 16B per lane, wave-uniform LDS base + lane*16
#define GLOAD_LDS16(g, l)                                              \
    __builtin_amdgcn_global_load_lds(                                  \
        (const __attribute__((address_space(1))) unsigned int*)(g),    \
        (__attribute__((address_space(3))) unsigned int*)(l), 16, 0, 0)

// RNE round-to-bf16 on bit patterns
__device__ inline unsigned short bf_round(float x, float& fv) {
    unsigned int u = __float_as_uint(x);
    unsigned int r = (u + 0x7fffu + ((u >> 16) & 1u)) & 0xffff0000u;
    fv = __uint_as_float(r);
    return (unsigned short)(r >> 16);
}

// ---------------------------------------------------------------------------
// K1a: q(c,b,f) = sum_e x(b,e) * Wq[c][f,e] + bq[c][f]
// Weight-stationary: block = (f-tile of 8, c); thread = (b, f_sub).
// ---------------------------------------------------------------------------
__global__ __launch_bounds__(256) void k_q2(
        const float* __restrict__ x, const float* __restrict__ Wq,
        const float* __restrict__ bq, float* __restrict__ q) {
    int ft = blockIdx.x, c = blockIdx.y;
    int f0 = ft * 8;
    __shared__ float wsm[8][66];
    __shared__ float xs[32][66];
    int tid = threadIdx.x;
    int b = tid & 31, fs = tid >> 5;
    float acc = 0.f;
    const float* W = Wq + (size_t)c * E_ * E_;
    for (int k0 = 0; k0 < E_; k0 += 64) {
        __syncthreads();
        for (int i = tid; i < 512; i += 256)
            wsm[i >> 6][i & 63] = W[(size_t)(f0 + (i >> 6)) * E_ + k0 + (i & 63)];
        for (int i = tid; i < 2048; i += 256)
            xs[i >> 6][i & 63] = x[(size_t)(i >> 6) * E_ + k0 + (i & 63)];
        __syncthreads();
        #pragma unroll
        for (int kk = 0; kk < 64; ++kk)
            acc += xs[b][kk] * wsm[fs][kk];
    }
    q[((size_t)c * B_ + b) * E_ + f0 + fs] = acc + bq[c * E_ + f0 + fs];
}

// ---------------------------------------------------------------------------
// K1b: u(c, m=(b*8+h), e) = sum_d q(c,b,h*64+d) * Wk[c][h*64+d, e]
// block = (e-tile of 64, h, c); thread = (b, e-group of 8). Wk read once.
// ---------------------------------------------------------------------------
__global__ __launch_bounds__(256) void k_u2(
        const float* __restrict__ q, const float* __restrict__ Wk,
        const float* __restrict__ bk, float* __restrict__ u,
        float* __restrict__ qb) {
    int et = blockIdx.x, h = blockIdx.y, c = blockIdx.z;
    int e0 = et * 64;
    __shared__ float qs[32][66];
    __shared__ float wk[64][66];
    int tid = threadIdx.x;
    int b = tid & 31, es = tid >> 5;
    for (int i = tid; i < 2048; i += 256)
        qs[i >> 6][i & 63] = q[((size_t)c * B_ + (i >> 6)) * E_ + h * 64 + (i & 63)];
    const float* W = Wk + (size_t)c * E_ * E_ + (size_t)(h * 64) * E_;
    for (int i = tid; i < 4096; i += 256)
        wk[i >> 6][i & 63] = W[(size_t)(i >> 6) * E_ + e0 + (i & 63)];
    __syncthreads();
    float acc[8] = {};
    for (int d = 0; d < 64; ++d) {
        float qv = qs[b][d];
        #pragma unroll
        for (int j = 0; j < 8; ++j)
            acc[j] += qv * wk[d][es * 8 + j];
    }
    float* urow = u + ((size_t)c * 256 + b * 8 + h) * E_ + e0 + es * 8;
    #pragma unroll
    for (int j = 0; j < 8; ++j) urow[j] = acc[j];
    if (et == 0 && es == 0) {
        float s = 0.f;
        const float* bkr = bk + c * E_ + h * 64;
        for (int d = 0; d < 64; ++d) s += qs[b][d] * bkr[d];
        qb[c * 256 + b * 8 + h] = s;
    }
}

// ---------------------------------------------------------------------------
// Split u into 3 bf16 planes in 32x32x16 A-fragment order:
//   u3[plane][c][mt(8)][ks(16)][kh(2)][lane(64)][8];
//   element = u[c][mt*32 + (lane&31)][ks*32 + kh*16 + (lane>>5)*8 + j]
// ---------------------------------------------------------------------------
#define U3_PLANE ((size_t)C_ * 8 * 16 * 2 * 64 * 8)   // 1,048,576 shorts

__global__ void k_split_u3(const float* __restrict__ u, short* __restrict__ u3) {
    int bx = blockIdx.x;                 // c*128 + mt*16 + ks
    int ks = bx & 15, mt = (bx >> 4) & 7, c = bx >> 7;
    int lane = threadIdx.x;
    int m = mt * 32 + (lane & 31);
    #pragma unroll
    for (int kh = 0; kh < 2; ++kh) {
        int k0 = ks * 32 + kh * 16 + (lane >> 5) * 8;
        const float* up = u + ((size_t)c * 256 + m) * 512 + k0;
        size_t base = ((((size_t)(c * 8 + mt) * 16 + ks) * 2 + kh) * 64 + lane) * 8;
        #pragma unroll
        for (int j = 0; j < 8; ++j) {
            float x = up[j], fh, fm, fl;
            unsigned short h = bf_round(x, fh);
            unsigned short mm = bf_round(x - fh, fm);
            unsigned short l = bf_round(x - fh - fm, fl);
            u3[base + j]                = (short)h;
            u3[U3_PLANE + base + j]     = (short)mm;
            u3[2 * U3_PLANE + base + j] = (short)l;
        }
    }
}

// ---------------------------------------------------------------------------
// Split A into 3 bf16 planes, tiled per (nchunk of 128, kstep of 32):
//   [3][128 n][32 k] LINEAR (12288 shorts / 24576 B per tile).
// 32x32 B-frag reads on this layout are <=2-way bank-aliased (free);
// GEMM staging is a straight 24 KB DMA.
// ---------------------------------------------------------------------------
__global__ void k_split_A3(const float* __restrict__ A, short* __restrict__ A3t) {
    int nc = blockIdx.x, ks = blockIdx.y;
    int tid = threadIdx.x;
    int n = tid >> 1, kg = (tid & 1) * 16;
    int gn = nc * 128 + n;
    const float* ap = A + (size_t)gn * 512 + ks * 32 + kg;
    bf8_t vh[2], vm[2], vl[2];
    #pragma unroll
    for (int g = 0; g < 2; ++g)
        #pragma unroll
        for (int j = 0; j < 8; ++j) {
            float x = (gn < N_) ? ap[g * 8 + j] : 0.f;
            float fh, fm, fl;
            unsigned short h = bf_round(x, fh);
            unsigned short mm = bf_round(x - fh, fm);
            unsigned short l = bf_round(x - fh - fm, fl);
            vh[g][j] = (short)h; vm[g][j] = (short)mm; vl[g][j] = (short)l;
        }
    short* outp = A3t + ((size_t)nc * 16 + ks) * 12288 + n * 32 + kg;
    #pragma unroll
    for (int g = 0; g < 2; ++g) {
        *(bf8_t*)(outp + g * 8)        = vh[g];
        *(bf8_t*)(outp + 4096 + g * 8) = vm[g];
        *(bf8_t*)(outp + 8192 + g * 8) = vl[g];
    }
}

// ---------------------------------------------------------------------------
// Main: S(m,n) = member ? exp(SCALE*(u·A + qb)) : 0, 6-product bf16x3 via
// 32x32x16 MFMA. Block: 256 thr (4 waves), tile M=256 x BN=128 per
// (class, nchunk). Wave w: m-tiles {2w,2w+1} x 4 n-tiles. 96 MFMA/ks/wave.
// A-tile staged via async global_load_lds (16B/lane). Fused row-sums.
// ---------------------------------------------------------------------------
#define MFMA32(a, b, c) __builtin_amdgcn_mfma_f32_32x32x16_bf16(a, b, c, 0, 0, 0)

__global__ __launch_bounds__(256, 2) void k_scores_mfma(
        const short* __restrict__ u3, const short* __restrict__ A3t,
        const float* __restrict__ qb, const int* __restrict__ mask,
        float* __restrict__ S, float* __restrict__ Zpart, int c0, int CB) {
    __shared__ __align__(16) short As[12288];   // [3][128][32] linear
    __shared__ float sQb[256];
    __shared__ int   sMask[128];
    int bx = blockIdx.x;
    int z  = bx % CB;
    int c  = c0 + z;
    int nc = bx / CB;
    int tid = threadIdx.x;
    int lane = tid & 63, w = tid >> 6;
    int half = lane >> 5, l31 = lane & 31;
    int n0 = nc * 128;

    sQb[tid] = qb[c * 256 + tid];
    if (tid < 128) {
        int n = n0 + tid;
        sMask[tid] = (n < N_) ? mask[(size_t)n * C_ + c] : 0;
    }

    f32x16 acc[2][4];
    #pragma unroll
    for (int i = 0; i < 2; ++i)
        #pragma unroll
        for (int j = 0; j < 4; ++j)
            acc[i][j] = (f32x16)(0.f);

    const char* tileBase = (const char*)A3t + (size_t)nc * (16 * 24576);

    for (int ks = 0; ks < 16; ++ks) {
        __syncthreads();
        // async DMA: 24 segments of 1024 B; wave w does segments w*6..w*6+5
        const char* src = tileBase + (size_t)ks * 24576;
        #pragma unroll
        for (int t = 0; t < 6; ++t) {
            int seg = w * 6 + t;
            GLOAD_LDS16(src + (size_t)seg * 1024 + lane * 16,
                        (char*)As + seg * 1024);
        }
        __syncthreads();   // compiler emits vmcnt(0) drain before barrier

        bf8_t af[2][2][3];   // [mt][kh][plane]
        #pragma unroll
        for (int mt = 0; mt < 2; ++mt)
            #pragma unroll
            for (int kh = 0; kh < 2; ++kh) {
                size_t ub = ((((size_t)(c * 8 + (w * 2 + mt)) * 16 + ks) * 2 + kh)
                             * 64 + lane) * 8;
                af[mt][kh][0] = *(const bf8_t*)(u3 + ub);
                af[mt][kh][1] = *(const bf8_t*)(u3 + U3_PLANE + ub);
                af[mt][kh][2] = *(const bf8_t*)(u3 + 2 * U3_PLANE + ub);
            }
        #pragma unroll
        for (int nt = 0; nt < 4; ++nt) {
            #pragma unroll
            for (int kh = 0; kh < 2; ++kh) {
                const short* bp = &As[(nt * 32 + l31) * 32 + kh * 16 + half * 8];
                bf8_t b0 = *(const bf8_t*)bp;
                bf8_t b1 = *(const bf8_t*)(bp + 4096);
                bf8_t b2 = *(const bf8_t*)(bp + 8192);
                #pragma unroll
                for (int mt = 0; mt < 2; ++mt) {
                    f32x16 a = acc[mt][nt];
                    a = MFMA32(af[mt][kh][0], b0, a);   // hh
                    a = MFMA32(af[mt][kh][0], b1, a);   // hm
                    a = MFMA32(af[mt][kh][1], b0, a);   // mh
                    a = MFMA32(af[mt][kh][1], b1, a);   // mm
                    a = MFMA32(af[mt][kh][0], b2, a);   // hl
                    a = MFMA32(af[mt][kh][2], b0, a);   // lh
                    acc[mt][nt] = a;
                }
            }
        }
    }

    // Epilogue: scale + bias + mask + exp, write S, fused deterministic row-sums.
    // C/D: col = lane&31, row = (reg&3) + 8*(reg>>2) + 4*half  (m74/m101)
    float* Sc = S + (size_t)z * SSZ;
    #pragma unroll
    for (int mt = 0; mt < 2; ++mt) {
        float rs[16];
        #pragma unroll
        for (int reg = 0; reg < 16; ++reg) rs[reg] = 0.f;
        #pragma unroll
        for (int nt = 0; nt < 4; ++nt) {
            int n = n0 + nt * 32 + l31;
            int mem = sMask[nt * 32 + l31];
            #pragma unroll
            for (int reg = 0; reg < 16; ++reg) {
                int m = w * 64 + mt * 32 + (reg & 3) + 8 * (reg >> 2) + 4 * half;
                float sc = SCALE * (acc[mt][nt][reg] + sQb[m]);
                float ev = mem ? __expf(sc) : 0.f;
                rs[reg] += ev;
                if (n < N_) Sc[(size_t)m * N_ + n] = ev;
            }
        }
        #pragma unroll
        for (int reg = 0; reg < 16; ++reg) {
            float v = rs[reg];
            v += __shfl_xor(v, 1); v += __shfl_xor(v, 2);
            v += __shfl_xor(v, 4); v += __shfl_xor(v, 8);
            v += __shfl_xor(v, 16);
            if (l31 == 0) {
                int m = w * 64 + mt * 32 + (reg & 3) + 8 * (reg >> 2) + 4 * half;
                Zpart[((size_t)nc * C_ + c) * 256 + m] = v;
            }
        }
    }
}

// ---------------------------------------------------------------------------
// Z(c,m) = sum_nc Zpart(nc,c,m). grid = CB blocks x 256 thr.
// ---------------------------------------------------------------------------
__global__ void k_zsum(const float* __restrict__ Zpart, float* __restrict__ Z, int c0) {
    int c = c0 + blockIdx.x;
    int i = c * 256 + threadIdx.x;
    float s = 0.f;
    for (int nc = 0; nc < NC3; ++nc) s += Zpart[(size_t)nc * (C_ * 256) + i];
    Z[i] = s;
}

// ---------------------------------------------------------------------------
// K3: fused head-average + chunk-local top-ns. grid (NCH, B, CB).
// ---------------------------------------------------------------------------
__global__ __launch_bounds__(256) void k_topk1(
        const float* __restrict__ S, const float* __restrict__ Z,
        float2* __restrict__ cand, int c0, int ns) {
    int chunk = blockIdx.x, b = blockIdx.y, z = blockIdx.z;
    const float* Sc = S + (size_t)z * SSZ;
    int tid = threadIdx.x;
    __shared__ float zr[H_];
    if (tid < H_) zr[tid] = 1.0f / Z[(c0 + z) * (B_ * H_) + b * H_ + tid];
    __syncthreads();
    int n0 = chunk * CHUNK;
    float v[2]; int ix[2];
    #pragma unroll
    for (int s = 0; s < 2; ++s) {
        int n = n0 + tid + s * 256;
        float a = -1.f;
        if (n < N_) {
            a = 0.f;
            #pragma unroll
            for (int h = 0; h < H_; ++h)
                a += Sc[(size_t)(b * H_ + h) * N_ + n] * zr[h];
            a *= (1.0f / H_);
        }
        v[s] = a; ix[s] = (n < N_) ? n : N_;
    }
    __shared__ float sv[256];
    __shared__ int   si[256];
    __shared__ int   win;
    for (int j = 0; j < ns; ++j) {
        float bv; int bi;
        if (v[0] > v[1] || (v[0] == v[1] && ix[0] < ix[1])) { bv = v[0]; bi = ix[0]; }
        else                                                 { bv = v[1]; bi = ix[1]; }
        sv[tid] = bv; si[tid] = bi;
        __syncthreads();
        for (int w = 128; w >= 1; w >>= 1) {
            if (tid < w) {
                float v2 = sv[tid + w]; int i2 = si[tid + w];
                if (v2 > sv[tid] || (v2 == sv[tid] && i2 < si[tid])) {
                    sv[tid] = v2; si[tid] = i2;
                }
            }
            __syncthreads();
        }
        if (tid == 0) {
            cand[(((size_t)z * B_ + b) * NCH + chunk) * ns + j] =
                make_float2(sv[0], (float)si[0]);
            win = si[0];
        }
        __syncthreads();
        if (ix[0] == win) v[0] = -2.f;
        if (ix[1] == win) v[1] = -2.f;
        __syncthreads();
    }
}

// ---------------------------------------------------------------------------
// K4: merge NCH*ns candidates -> final top-ns per (b, class). grid (B, CB).
// ---------------------------------------------------------------------------
__global__ __launch_bounds__(256) void k_topk2(
        const float2* __restrict__ cand, float* __restrict__ out, int c0, int ns) {
    int b = blockIdx.x, z = blockIdx.y;
    int c = c0 + z;
    int tid = threadIdx.x;
    int ncand = NCH * ns;
    const float2* cb = cand + ((size_t)z * B_ + b) * ncand;
    float v = -3.f; int ix = N_ + 1;
    if (tid < ncand) { float2 e = cb[tid]; v = e.x; ix = (int)e.y; }
    __shared__ float sv[256];
    __shared__ int   si[256];
    __shared__ int   win;
    for (int j = 0; j < ns; ++j) {
        sv[tid] = v; si[tid] = ix;
        __syncthreads();
        for (int w = 128; w >= 1; w >>= 1) {
            if (tid < w) {
                float v2 = sv[tid + w]; int i2 = si[tid + w];
                if (v2 > sv[tid] || (v2 == sv[tid] && i2 < si[tid])) {
                    sv[tid] = v2; si[tid] = i2;
                }
            }
            __syncthreads();
        }
        if (tid == 0) {
            out[((size_t)b * C_ + c) * ns + j] = (float)si[0];
            out[(size_t)B_ * C_ * ns + ((size_t)b * C_ + c) * ns + j] = sv[0];
            win = si[0];
        }
        __syncthreads();
        if (ix == win) v = -3.f;
        __syncthreads();
    }
}

// ---------------------------------------------------------------------------
extern "C" void kernel_launch(void* const* d_in, const int* in_sizes, int n_in,
                              void* d_out, int out_size, void* d_ws, size_t ws_size,
                              hipStream_t stream) {
    const float* x    = (const float*)d_in[0];  // (B,E)
    const float* A    = (const float*)d_in[1];  // (N,E)
    const int*   mask = (const int*)  d_in[2];  // (N,C)
    const float* Wq   = (const float*)d_in[3];  // (C,E,E)
    const float* bq   = (const float*)d_in[4];  // (C,E)
    const float* Wk   = (const float*)d_in[5];  // (C,E,E)
    const float* bk   = (const float*)d_in[6];  // (C,E)
    float* out = (float*)d_out;

    int ns = out_size / (2 * B_ * C_);          // = n_samples (5)

    // Workspace carve (floats)
    float* ws = (float*)d_ws;
    float* q     = ws;                                    // 131072
    float* u     = q     + (size_t)C_ * B_ * E_;          // 1048576
    float* qb    = u     + (size_t)C_ * B_ * H_ * E_;     // 2048
    float* Z     = qb    + (size_t)C_ * B_ * H_;          // 2048
    float* Zpart = Z     + (size_t)C_ * B_ * H_;          // NC3*8*256 = 321536
    short* u3    = (short*)(Zpart + (size_t)NC3 * C_ * 256);   // 3*1048576 shorts
    short* A3t   = u3 + 3 * U3_PLANE;                          // NC3*16*12288 shorts
    float* S     = (float*)(A3t + (size_t)NC3 * 16 * 12288);
    size_t fixedFloats = (size_t)(S - ws);

    size_t candFloats = (size_t)C_ * B_ * NCH * ns * 2;
    int CB = 8;
    while (CB > 1 &&
           (fixedFloats + (size_t)CB * SSZ + candFloats + 16) * 4 > ws_size)
        CB >>= 1;
    float2* cand = (float2*)(S + (size_t)CB * SSZ);

    k_q2<<<dim3(64, C_), 256, 0, stream>>>(x, Wq, bq, q);
    k_u2<<<dim3(8, H_, C_), 256, 0, stream>>>(q, Wk, bk, u, qb);
    k_split_u3<<<C_ * 8 * 16, 64, 0, stream>>>(u, u3);
    k_split_A3<<<dim3(NC3, 16), 256, 0, stream>>>(A, A3t);

    for (int c0 = 0; c0 < C_; c0 += CB) {
        k_scores_mfma<<<NC3 * CB, 256, 0, stream>>>(u3, A3t, qb, mask, S, Zpart, c0, CB);
        k_zsum<<<CB, 256, 0, stream>>>(Zpart, Z, c0);
        k_topk1<<<dim3(NCH, B_, CB), 256, 0, stream>>>(S, Z, cand, c0, ns);
        k_topk2<<<dim3(B_, CB), 256, 0, stream>>>(cand, out, c0, ns);
    }
}